// Round 4
// baseline (149.515 us; speedup 1.0000x reference)
//
#include <hip/hip_runtime.h>
#include <stdint.h>

// Problem dims
#define TDIM 4096
#define HDIM 2048   // N and K of the GEMM

// GEMM tile
#define BM 128
#define BN 128
#define BK 32
#define NKT (HDIM / BK)   // 64
// LDS layout: per buffer = A region (144 rows = 9 groups of 16 rows, 1KB/group)
//             + B region (128 rows = 8 groups), 64B per row (BK=32 bf16)
#define PERBUF 17408
#define BOFF   9216
#define SSTR   132        // S-tile row stride in elements (breaks bank conflicts)

typedef short short8 __attribute__((ext_vector_type(8)));
typedef float f32x4 __attribute__((ext_vector_type(4)));

__device__ __forceinline__ uint16_t f2bf(float f) {
  uint32_t u = __builtin_bit_cast(uint32_t, f);
  u += 0x7fffu + ((u >> 16) & 1u);          // round-to-nearest-even
  return (uint16_t)(u >> 16);
}
__device__ __forceinline__ float bf2f(uint32_t h) {   // low 16 bits used
  uint32_t u = h << 16;
  return __builtin_bit_cast(float, u);
}

__device__ __forceinline__ void async_copy16(const void* gsrc, void* ldst) {
  __builtin_amdgcn_global_load_lds(
      (const __attribute__((address_space(1))) uint32_t*)gsrc,
      (__attribute__((address_space(3))) uint32_t*)ldst,
      16, 0, 0);
}

// ------------- prep: cvt x (fp32->bf16) + transpose/cvt B -> Bt -------------
__global__ void prep(const float* __restrict__ x, const float* __restrict__ B,
                     uint16_t* __restrict__ xb, uint16_t* __restrict__ Bt) {
  __shared__ uint16_t tile[64][68];
  const int t = threadIdx.x;
  if (blockIdx.x < 4096) {
    size_t i = ((size_t)blockIdx.x * 256 + t) * 8;
    float4 v0 = *(const float4*)(x + i);
    float4 v1 = *(const float4*)(x + i + 4);
    union { uint16_t h[8]; uint4 v; } o;
    o.h[0] = f2bf(v0.x); o.h[1] = f2bf(v0.y); o.h[2] = f2bf(v0.z); o.h[3] = f2bf(v0.w);
    o.h[4] = f2bf(v1.x); o.h[5] = f2bf(v1.y); o.h[6] = f2bf(v1.z); o.h[7] = f2bf(v1.w);
    *(uint4*)(xb + i) = o.v;
  } else {
    const int bid = blockIdx.x - 4096;
    const int n0 = (bid & 31) * 64;
    const int k0 = (bid >> 5) * 64;
    {
      const int r  = t >> 4;
      const int c4 = (t & 15) * 4;
#pragma unroll
      for (int i = 0; i < 4; ++i) {
        int rr = r + i * 16;
        float4 v = *(const float4*)&B[(size_t)(k0 + rr) * HDIM + n0 + c4];
        union { uint16_t h[4]; uint2 u; } o;
        o.h[0] = f2bf(v.x); o.h[1] = f2bf(v.y); o.h[2] = f2bf(v.z); o.h[3] = f2bf(v.w);
        *(uint2*)&tile[rr][c4] = o.u;
      }
    }
    __syncthreads();
    {
      const int nr = t >> 2;
      const int kc = (t & 3) * 4;
#pragma unroll
      for (int i = 0; i < 4; ++i) {
        int kk = kc + i * 16;
        union { uint16_t h[4]; uint2 u; } o;
        o.h[0] = tile[kk][nr];     o.h[1] = tile[kk + 1][nr];
        o.h[2] = tile[kk + 2][nr]; o.h[3] = tile[kk + 3][nr];
        *(uint2*)&Bt[(size_t)(n0 + nr) * HDIM + k0 + kk] = o.u;
      }
    }
  }
}

// --------- fused GEMM + causal exp-decay recurrence (scan) ---------
// S[t][n] = sum_k A[t][k]*Bt[n][k]; out[t][h] = S[t][h] + a[h]*out[t-1][h].
// Block computes S-tile for t in [m0-16, m0+128) (16 warmup rows), holds it
// in LDS, then scans 2 t-chunks of 64 per column with 16-step warmup
// (|a| <= 2^-5 -> truncation ~1e-24).
__global__ __launch_bounds__(256, 2) void gemm_scan(
    const uint16_t* __restrict__ A, const uint16_t* __restrict__ Bt,
    const float* __restrict__ a, float* __restrict__ out) {
  __shared__ __align__(16) char lds[38016];   // max(2*PERBUF=34816, 144*132*2=38016)

  const int tid  = threadIdx.x;
  const int lane = tid & 63;
  const int wave = tid >> 6;            // 0..3
  const int wm = (wave >> 1) * 64;      // wave row offset {0,64}
  const int wn = (wave & 1) * 64;       // wave col offset {0,64}
  const int m0 = blockIdx.y * BM;
  const int n0 = blockIdx.x * BN;

  f32x4 acc[4][4] = {};
  f32x4 accw[4] = {};                   // warmup rows (waves 0,1 only)

  // staging: one instr = 16 rows x 64B; lane l: row lr=l>>2, slot l&3,
  // fetches global chunk (l&3)^(lr&3) -> LDS slot c holds chunk c^(row&3)
  const int lr = lane >> 2;             // 0..15
  const int gc = (lane & 3) ^ (lr & 3); // swizzled 16B chunk to fetch

  const int fr = lane & 15;
  const int fq = lane >> 4;             // 0..3

  auto issue_tile = [&](int kt2) {
    size_t koff = (size_t)kt2 * (BK * 2);
    char* dst = lds + (kt2 & 1) * PERBUF;
    // A: 9 groups (rows m0-16 .. m0+128), wave w takes g = w, w+4, w+8
    for (int g = wave; g < 9; g += 4) {
      int row = m0 - 16 + g * 16 + lr;
      if (row < 0) row = 0;             // m0==0: garbage rows, never read
      async_copy16((const char*)A + ((size_t)row * HDIM + gc * 8) * 2 + koff,
                   dst + g * 1024);
    }
    // B: 8 groups (rows n0 .. n0+128)
    for (int g = wave; g < 8; g += 4) {
      int row = n0 + g * 16 + lr;
      async_copy16((const char*)Bt + ((size_t)row * HDIM + gc * 8) * 2 + koff,
                   dst + BOFF + g * 1024);
    }
  };

  issue_tile(0);
  for (int kt = 0; kt < NKT; ++kt) {
    if (kt + 1 < NKT) {
      issue_tile(kt + 1);
      // wait only this tile's loads; next tile's (5 or 4) stay in flight
      if (wave == 0) asm volatile("s_waitcnt vmcnt(5)" ::: "memory");
      else           asm volatile("s_waitcnt vmcnt(4)" ::: "memory");
    } else {
      asm volatile("s_waitcnt vmcnt(0)" ::: "memory");
    }
    asm volatile("s_barrier" ::: "memory");

    const char* base = lds + (kt & 1) * PERBUF;
    short8 af[4], bfr[4], aw;
#pragma unroll
    for (int im = 0; im < 4; ++im) {
      int row = 16 + wm + im * 16 + fr;                 // row&3 == fr&3
      af[im] = *(const short8*)(base + row * 64 + ((fq ^ (fr & 3)) * 16));
    }
#pragma unroll
    for (int in = 0; in < 4; ++in) {
      int row = wn + in * 16 + fr;
      bfr[in] = *(const short8*)(base + BOFF + row * 64 + ((fq ^ (fr & 3)) * 16));
    }
#pragma unroll
    for (int im = 0; im < 4; ++im)
#pragma unroll
      for (int in = 0; in < 4; ++in)
        acc[im][in] = __builtin_amdgcn_mfma_f32_16x16x32_bf16(
            af[im], bfr[in], acc[im][in], 0, 0, 0);
    if (wave < 2) {                     // warmup rows t in [m0-16, m0)
      aw = *(const short8*)(base + fr * 64 + ((fq ^ (fr & 3)) * 16));
#pragma unroll
      for (int in = 0; in < 4; ++in)
        accw[in] = __builtin_amdgcn_mfma_f32_16x16x32_bf16(
            aw, bfr[in], accw[in], 0, 0, 0);
    }

    asm volatile("s_barrier" ::: "memory");   // buf consumed; safe to refill
  }

  // ---- epilogue: S-tile (144 x 128, bf16, stride 132) into LDS ----
  uint16_t* Sl = (uint16_t*)lds;
#pragma unroll
  for (int im = 0; im < 4; ++im)
#pragma unroll
    for (int in = 0; in < 4; ++in)
#pragma unroll
      for (int r = 0; r < 4; ++r)
        Sl[(16 + wm + im * 16 + fq * 4 + r) * SSTR + wn + in * 16 + fr] =
            f2bf(acc[im][in][r]);
  if (wave < 2) {
#pragma unroll
    for (int in = 0; in < 4; ++in)
#pragma unroll
      for (int r = 0; r < 4; ++r)
        Sl[(fq * 4 + r) * SSTR + wn + in * 16 + fr] = f2bf(accw[in][r]);
  }
  __syncthreads();

  // ---- scan: 2 threads per column, 64 t-steps each, 16-step warmup ----
  const int col   = tid & 127;
  const int chunk = tid >> 7;           // 0 or 1
  const float av  = a[n0 + col];
  float h = 0.f;
  if (!(m0 == 0 && chunk == 0)) {
#pragma unroll
    for (int i = 0; i < 16; ++i)
      h = av * h + bf2f(Sl[(chunk * 64 + i) * SSTR + col]);
  }
  float* op = out + (size_t)(m0 + chunk * 64) * HDIM + n0 + col;
#pragma unroll
  for (int i = 0; i < 64; ++i) {
    h = av * h + bf2f(Sl[(16 + chunk * 64 + i) * SSTR + col]);
    op[(size_t)i * HDIM] = h;
  }
}

extern "C" void kernel_launch(void* const* d_in, const int* in_sizes, int n_in,
                              void* d_out, int out_size, void* d_ws, size_t ws_size,
                              hipStream_t stream) {
  const float* x = (const float*)d_in[0];   // (T, H)
  const float* a = (const float*)d_in[1];   // (H,)
  const float* B = (const float*)d_in[2];   // (H, H)
  float* out = (float*)d_out;               // (1, T, H) fp32

  uint16_t* xb  = (uint16_t*)d_ws;                                        // 16 MB
  uint16_t* Btb = (uint16_t*)((char*)d_ws + (size_t)16 * 1024 * 1024);    //  8 MB

  // x -> bf16  and  B -> Bt bf16 (fused)
  prep<<<4096 + 1024, 256, 0, stream>>>(x, B, xb, Btb);
  // fused GEMM + recurrence: 512 blocks x 256 threads
  gemm_scan<<<dim3(HDIM / BN, TDIM / BM), 256, 0, stream>>>(xb, Btb, a, out);
}

// Round 5
// 143.629 us; speedup vs baseline: 1.0410x; 1.0410x over previous
//
#include <hip/hip_runtime.h>
#include <stdint.h>

// Problem dims
#define TDIM 4096
#define HDIM 2048   // N and K of the GEMM

// GEMM tile
#define BM 128
#define BN 128
#define BK 32
#define NKT (HDIM / BK)   // 64
// LDS: per buffer = A region (144 rows = 9 groups of 16 rows, 1KB/group)
//      + B region (128 rows = 8 groups), 64B per row (BK=32 bf16)
#define PERBUF 17408
#define BOFF   9216
#define SSTR   132        // S-tile row stride in elements (breaks bank conflicts)

typedef short short8 __attribute__((ext_vector_type(8)));
typedef float f32x4 __attribute__((ext_vector_type(4)));

__device__ __forceinline__ uint16_t f2bf(float f) {
  uint32_t u = __builtin_bit_cast(uint32_t, f);
  u += 0x7fffu + ((u >> 16) & 1u);          // round-to-nearest-even
  return (uint16_t)(u >> 16);
}
__device__ __forceinline__ float bf2f(uint32_t h) {   // low 16 bits used
  uint32_t u = h << 16;
  return __builtin_bit_cast(float, u);
}

__device__ __forceinline__ void async_copy16(const void* gsrc, void* ldst) {
  __builtin_amdgcn_global_load_lds(
      (const __attribute__((address_space(1))) uint32_t*)gsrc,
      (__attribute__((address_space(3))) uint32_t*)ldst,
      16, 0, 0);
}

// ------------- prep: cvt x (fp32->bf16) + transpose/cvt B -> Bt -------------
__global__ void prep(const float* __restrict__ x, const float* __restrict__ B,
                     uint16_t* __restrict__ xb, uint16_t* __restrict__ Bt) {
  __shared__ uint16_t tile[64][68];
  const int t = threadIdx.x;
  if (blockIdx.x < 4096) {
    size_t i = ((size_t)blockIdx.x * 256 + t) * 8;
    float4 v0 = *(const float4*)(x + i);
    float4 v1 = *(const float4*)(x + i + 4);
    union { uint16_t h[8]; uint4 v; } o;
    o.h[0] = f2bf(v0.x); o.h[1] = f2bf(v0.y); o.h[2] = f2bf(v0.z); o.h[3] = f2bf(v0.w);
    o.h[4] = f2bf(v1.x); o.h[5] = f2bf(v1.y); o.h[6] = f2bf(v1.z); o.h[7] = f2bf(v1.w);
    *(uint4*)(xb + i) = o.v;
  } else {
    const int bid = blockIdx.x - 4096;
    const int n0 = (bid & 31) * 64;
    const int k0 = (bid >> 5) * 64;
    {
      const int r  = t >> 4;
      const int c4 = (t & 15) * 4;
#pragma unroll
      for (int i = 0; i < 4; ++i) {
        int rr = r + i * 16;
        float4 v = *(const float4*)&B[(size_t)(k0 + rr) * HDIM + n0 + c4];
        union { uint16_t h[4]; uint2 u; } o;
        o.h[0] = f2bf(v.x); o.h[1] = f2bf(v.y); o.h[2] = f2bf(v.z); o.h[3] = f2bf(v.w);
        *(uint2*)&tile[rr][c4] = o.u;
      }
    }
    __syncthreads();
    {
      const int nr = t >> 2;
      const int kc = (t & 3) * 4;
#pragma unroll
      for (int i = 0; i < 4; ++i) {
        int kk = kc + i * 16;
        union { uint16_t h[4]; uint2 u; } o;
        o.h[0] = tile[kk][nr];     o.h[1] = tile[kk + 1][nr];
        o.h[2] = tile[kk + 2][nr]; o.h[3] = tile[kk + 3][nr];
        *(uint2*)&Bt[(size_t)(n0 + nr) * HDIM + k0 + kk] = o.u;
      }
    }
  }
}

// --------- fused GEMM + causal exp-decay recurrence (scan) ---------
// S[t][n] = sum_k A[t][k]*Bt[n][k]; out[t][h] = S[t][h] + a[h]*out[t-1][h].
// 512 threads = 8 waves (2x4 grid of 64x32 wave tiles) -> 16 waves/CU at
// 2 blocks/CU: restores R3's TLP. Block computes S for t in [m0-16, m0+128)
// (16 warmup rows on waves 0-3), keeps it in LDS, then scans 4 t-chunks of
// 32 per column with 16-step warmup (|a| <= 2^-5 -> truncation ~1e-24).
__global__ __launch_bounds__(512, 4) void gemm_scan(
    const uint16_t* __restrict__ A, const uint16_t* __restrict__ Bt,
    const float* __restrict__ a, float* __restrict__ out) {
  __shared__ __align__(16) char lds[38016];   // max(2*PERBUF=34816, 144*132*2)

  const int tid  = threadIdx.x;
  const int lane = tid & 63;
  const int wave = tid >> 6;            // 0..7
  const int wm = (wave >> 2) * 64;      // wave row offset {0,64}
  const int wn = (wave & 3) * 32;       // wave col offset {0,32,64,96}
  const int m0 = blockIdx.y * BM;
  const int n0 = blockIdx.x * BN;

  f32x4 acc[4][2] = {};
  f32x4 accw[2] = {};                   // warmup rows (waves 0-3 only)

  // staging: one instr = 16 rows x 64B; lane l: row lr=l>>2, slot l&3,
  // fetches global chunk (l&3)^(lr&3) -> LDS slot c holds chunk c^(row&3)
  const int lr = lane >> 2;             // 0..15
  const int gc = (lane & 3) ^ (lr & 3); // swizzled 16B chunk to fetch

  const int fr = lane & 15;
  const int fq = lane >> 4;             // 0..3

  auto issue_tile = [&](int kt2) {
    size_t koff = (size_t)kt2 * (BK * 2);
    char* dst = lds + (kt2 & 1) * PERBUF;
    // A: 9 groups (rows m0-16 .. m0+128); wave w takes g = w (+8 for wave 0)
#pragma unroll
    for (int g = wave; g < 9; g += 8) {
      int row = m0 - 16 + g * 16 + lr;
      if (row < 0) row = 0;             // m0==0: garbage rows, never read
      async_copy16((const char*)A + ((size_t)row * HDIM + gc * 8) * 2 + koff,
                   dst + g * 1024);
    }
    // B: 8 groups (rows n0 .. n0+128); wave w takes g = w
    {
      int g = wave;
      int row = n0 + g * 16 + lr;
      async_copy16((const char*)Bt + ((size_t)row * HDIM + gc * 8) * 2 + koff,
                   dst + BOFF + g * 1024);
    }
  };

  issue_tile(0);
  for (int kt = 0; kt < NKT; ++kt) {
    if (kt + 1 < NKT) {
      issue_tile(kt + 1);
      // wait only this tile's loads; next tile's stay in flight
      if (wave == 0) asm volatile("s_waitcnt vmcnt(3)" ::: "memory");
      else           asm volatile("s_waitcnt vmcnt(2)" ::: "memory");
    } else {
      asm volatile("s_waitcnt vmcnt(0)" ::: "memory");
    }
    asm volatile("s_barrier" ::: "memory");

    const char* base = lds + (kt & 1) * PERBUF;
    short8 af[4], bfr[2], aw;
#pragma unroll
    for (int im = 0; im < 4; ++im) {
      int row = 16 + wm + im * 16 + fr;                 // row&3 == fr&3
      af[im] = *(const short8*)(base + row * 64 + ((fq ^ (fr & 3)) * 16));
    }
#pragma unroll
    for (int in = 0; in < 2; ++in) {
      int row = wn + in * 16 + fr;
      bfr[in] = *(const short8*)(base + BOFF + row * 64 + ((fq ^ (fr & 3)) * 16));
    }
#pragma unroll
    for (int im = 0; im < 4; ++im)
#pragma unroll
      for (int in = 0; in < 2; ++in)
        acc[im][in] = __builtin_amdgcn_mfma_f32_16x16x32_bf16(
            af[im], bfr[in], acc[im][in], 0, 0, 0);
    if (wave < 4) {                     // warmup rows t in [m0-16, m0)
      aw = *(const short8*)(base + fr * 64 + ((fq ^ (fr & 3)) * 16));
#pragma unroll
      for (int in = 0; in < 2; ++in)
        accw[in] = __builtin_amdgcn_mfma_f32_16x16x32_bf16(
            aw, bfr[in], accw[in], 0, 0, 0);
    }

    asm volatile("s_barrier" ::: "memory");   // buf consumed; safe to refill
  }

  // ---- epilogue: S-tile (144 x 128, bf16, stride 132) into LDS ----
  asm volatile("s_barrier" ::: "memory");     // all MFMA consumers done
  uint16_t* Sl = (uint16_t*)lds;
#pragma unroll
  for (int im = 0; im < 4; ++im)
#pragma unroll
    for (int in = 0; in < 2; ++in)
#pragma unroll
      for (int r = 0; r < 4; ++r)
        Sl[(16 + wm + im * 16 + fq * 4 + r) * SSTR + wn + in * 16 + fr] =
            f2bf(acc[im][in][r]);
  if (wave < 4) {
#pragma unroll
    for (int in = 0; in < 2; ++in)
#pragma unroll
      for (int r = 0; r < 4; ++r)
        Sl[(fq * 4 + r) * SSTR + wn + in * 16 + fr] = f2bf(accw[in][r]);
  }
  __syncthreads();

  // ---- scan: 4 threads per column, 32 t-steps each, 16-step warmup ----
  const int col   = tid & 127;
  const int chunk = tid >> 7;           // 0..3
  const float av  = a[n0 + col];
  float h = 0.f;
  if (!(m0 == 0 && chunk == 0)) {
#pragma unroll
    for (int i = 0; i < 16; ++i)
      h = av * h + bf2f(Sl[(chunk * 32 + i) * SSTR + col]);
  }
  float* op = out + (size_t)(m0 + chunk * 32) * HDIM + n0 + col;
#pragma unroll
  for (int i = 0; i < 32; ++i) {
    h = av * h + bf2f(Sl[(chunk * 32 + 16 + i) * SSTR + col]);
    op[(size_t)i * HDIM] = h;
  }
}

extern "C" void kernel_launch(void* const* d_in, const int* in_sizes, int n_in,
                              void* d_out, int out_size, void* d_ws, size_t ws_size,
                              hipStream_t stream) {
  const float* x = (const float*)d_in[0];   // (T, H)
  const float* a = (const float*)d_in[1];   // (H,)
  const float* B = (const float*)d_in[2];   // (H, H)
  float* out = (float*)d_out;               // (1, T, H) fp32

  uint16_t* xb  = (uint16_t*)d_ws;                                        // 16 MB
  uint16_t* Btb = (uint16_t*)((char*)d_ws + (size_t)16 * 1024 * 1024);    //  8 MB

  // x -> bf16  and  B -> Bt bf16 (fused)
  prep<<<4096 + 1024, 256, 0, stream>>>(x, B, xb, Btb);
  // fused GEMM + recurrence: 512 blocks x 512 threads
  gemm_scan<<<dim3(HDIM / BN, TDIM / BM), 512, 0, stream>>>(xb, Btb, a, out);
}

// Round 6
// 139.544 us; speedup vs baseline: 1.0715x; 1.0293x over previous
//
#include <hip/hip_runtime.h>
#include <stdint.h>

// Problem dims
#define TDIM 4096
#define HDIM 2048   // N and K of the GEMM

// GEMM tile
#define BM 128
#define BN 128
#define BK 64
#define NKT (HDIM / BK)   // 32
// LDS: per buffer = A region (144 rows = 18 groups of 8 rows, 1KB/group)
//      + B region (128 rows = 16 groups), 128B per row (BK=64 bf16)
#define AREG  18432
#define PERBUF 34816
#define SSTR   132        // S-tile row stride in elements (breaks bank conflicts)

typedef short short8 __attribute__((ext_vector_type(8)));
typedef float f32x4 __attribute__((ext_vector_type(4)));

__device__ __forceinline__ uint16_t f2bf(float f) {
  uint32_t u = __builtin_bit_cast(uint32_t, f);
  u += 0x7fffu + ((u >> 16) & 1u);          // round-to-nearest-even
  return (uint16_t)(u >> 16);
}
__device__ __forceinline__ float bf2f(uint32_t h) {   // low 16 bits used
  uint32_t u = h << 16;
  return __builtin_bit_cast(float, u);
}

__device__ __forceinline__ void async_copy16(const void* gsrc, void* ldst) {
  __builtin_amdgcn_global_load_lds(
      (const __attribute__((address_space(1))) uint32_t*)gsrc,
      (__attribute__((address_space(3))) uint32_t*)ldst,
      16, 0, 0);
}

// ------------- prep: cvt x (fp32->bf16) + transpose/cvt B -> Bt -------------
__global__ void prep(const float* __restrict__ x, const float* __restrict__ B,
                     uint16_t* __restrict__ xb, uint16_t* __restrict__ Bt) {
  __shared__ uint16_t tile[64][68];
  const int t = threadIdx.x;
  if (blockIdx.x < 4096) {
    size_t i = ((size_t)blockIdx.x * 256 + t) * 8;
    float4 v0 = *(const float4*)(x + i);
    float4 v1 = *(const float4*)(x + i + 4);
    union { uint16_t h[8]; uint4 v; } o;
    o.h[0] = f2bf(v0.x); o.h[1] = f2bf(v0.y); o.h[2] = f2bf(v0.z); o.h[3] = f2bf(v0.w);
    o.h[4] = f2bf(v1.x); o.h[5] = f2bf(v1.y); o.h[6] = f2bf(v1.z); o.h[7] = f2bf(v1.w);
    *(uint4*)(xb + i) = o.v;
  } else {
    const int bid = blockIdx.x - 4096;
    const int n0 = (bid & 31) * 64;
    const int k0 = (bid >> 5) * 64;
    {
      const int r  = t >> 4;
      const int c4 = (t & 15) * 4;
#pragma unroll
      for (int i = 0; i < 4; ++i) {
        int rr = r + i * 16;
        float4 v = *(const float4*)&B[(size_t)(k0 + rr) * HDIM + n0 + c4];
        union { uint16_t h[4]; uint2 u; } o;
        o.h[0] = f2bf(v.x); o.h[1] = f2bf(v.y); o.h[2] = f2bf(v.z); o.h[3] = f2bf(v.w);
        *(uint2*)&tile[rr][c4] = o.u;
      }
    }
    __syncthreads();
    {
      const int nr = t >> 2;
      const int kc = (t & 3) * 4;
#pragma unroll
      for (int i = 0; i < 4; ++i) {
        int kk = kc + i * 16;
        union { uint16_t h[4]; uint2 u; } o;
        o.h[0] = tile[kk][nr];     o.h[1] = tile[kk + 1][nr];
        o.h[2] = tile[kk + 2][nr]; o.h[3] = tile[kk + 3][nr];
        *(uint2*)&Bt[(size_t)(n0 + nr) * HDIM + k0 + kk] = o.u;
      }
    }
  }
}

// --------- fused GEMM + causal exp-decay recurrence (scan) ---------
// S[t][n] = sum_k A[t][k]*Bt[n][k]; out[t][h] = S[t][h] + a[h]*out[t-1][h].
// 512 threads = 8 waves (2x4 grid of 64x32 wave tiles), 2 blocks/CU ->
// 16 waves/CU. BK=64: 128B LDS rows span all 32 banks; XOR-8 chunk swizzle
// gives conflict-free (2-way only) b128 reads. 16 warmup rows on waves 0-3;
// in-LDS S-tile scan epilogue (|a| <= 2^-5 -> 16-step truncation ~1e-24).
__global__ __launch_bounds__(512, 4) void gemm_scan(
    const uint16_t* __restrict__ A, const uint16_t* __restrict__ Bt,
    const float* __restrict__ a, float* __restrict__ out) {
  __shared__ __align__(16) char lds[2 * PERBUF];   // 69632 >= 144*132*2=38016

  const int tid  = threadIdx.x;
  const int lane = tid & 63;
  const int wave = tid >> 6;            // 0..7
  const int wm = (wave >> 2) * 64;      // wave row offset {0,64}
  const int wn = (wave & 3) * 32;       // wave col offset {0,32,64,96}
  const int m0 = blockIdx.y * BM;
  const int n0 = blockIdx.x * BN;

  f32x4 acc[4][2] = {};
  f32x4 accw[2] = {};                   // warmup rows (waves 0-3 only)

  // staging: one instr = 8 rows x 128B (1KB); lane l: row lr=l>>3, slot l&7,
  // fetches global chunk (l&7)^lr -> LDS slot c of row r holds chunk c^(r&7)
  const int lr = lane >> 3;             // 0..7
  const int gc = (lane & 7) ^ lr;       // swizzled 16B chunk to fetch

  const int fr = lane & 15;
  const int fq = lane >> 4;             // 0..3

  auto issue_tile = [&](int kt2) {
    size_t koff = (size_t)kt2 * (BK * 2);
    char* dst = lds + (kt2 & 1) * PERBUF;
    // A: 18 groups of 8 rows (rows m0-16 .. m0+128); wave w: g = w, w+8, w+16
#pragma unroll
    for (int g = wave; g < 18; g += 8) {
      int row = m0 - 16 + g * 8 + lr;
      if (row < 0) row = 0;             // m0==0: garbage rows, never used
      async_copy16((const char*)A + ((size_t)row * HDIM + gc * 8) * 2 + koff,
                   dst + g * 1024);
    }
    // B: 16 groups (rows n0 .. n0+128); wave w: g = w, w+8
#pragma unroll
    for (int g = wave; g < 16; g += 8) {
      int row = n0 + g * 8 + lr;
      async_copy16((const char*)Bt + ((size_t)row * HDIM + gc * 8) * 2 + koff,
                   dst + AREG + g * 1024);
    }
  };

  issue_tile(0);
  for (int kt = 0; kt < NKT; ++kt) {
    if (kt + 1 < NKT) {
      issue_tile(kt + 1);
      // wait only this tile's loads; next tile's (5 or 4) stay in flight
      if (wave < 2) asm volatile("s_waitcnt vmcnt(5)" ::: "memory");
      else          asm volatile("s_waitcnt vmcnt(4)" ::: "memory");
    } else {
      asm volatile("s_waitcnt vmcnt(0)" ::: "memory");
    }
    asm volatile("s_barrier" ::: "memory");

    const char* base = lds + (kt & 1) * PERBUF;
#pragma unroll
    for (int s = 0; s < 2; ++s) {       // two K=32 halves of the 128B row
      short8 af[4], bfr[2], aw;
#pragma unroll
      for (int im = 0; im < 4; ++im) {
        int row = 16 + wm + im * 16 + fr;               // row&7 == fr&7
        af[im] = *(const short8*)(base + row * 128 + (((s * 4 + fq) ^ (fr & 7)) * 16));
      }
#pragma unroll
      for (int in = 0; in < 2; ++in) {
        int row = wn + in * 16 + fr;
        bfr[in] = *(const short8*)(base + AREG + row * 128 + (((s * 4 + fq) ^ (fr & 7)) * 16));
      }
#pragma unroll
      for (int im = 0; im < 4; ++im)
#pragma unroll
        for (int in = 0; in < 2; ++in)
          acc[im][in] = __builtin_amdgcn_mfma_f32_16x16x32_bf16(
              af[im], bfr[in], acc[im][in], 0, 0, 0);
      if (wave < 4) {                   // warmup rows t in [m0-16, m0)
        aw = *(const short8*)(base + fr * 128 + (((s * 4 + fq) ^ (fr & 7)) * 16));
#pragma unroll
        for (int in = 0; in < 2; ++in)
          accw[in] = __builtin_amdgcn_mfma_f32_16x16x32_bf16(
              aw, bfr[in], accw[in], 0, 0, 0);
      }
    }

    asm volatile("s_barrier" ::: "memory");   // buf consumed; safe to refill
  }

  // ---- epilogue: S-tile (144 x 128, bf16, stride 132) into LDS ----
  uint16_t* Sl = (uint16_t*)lds;
#pragma unroll
  for (int im = 0; im < 4; ++im)
#pragma unroll
    for (int in = 0; in < 2; ++in)
#pragma unroll
      for (int r = 0; r < 4; ++r)
        Sl[(16 + wm + im * 16 + fq * 4 + r) * SSTR + wn + in * 16 + fr] =
            f2bf(acc[im][in][r]);
  if (wave < 4) {
#pragma unroll
    for (int in = 0; in < 2; ++in)
#pragma unroll
      for (int r = 0; r < 4; ++r)
        Sl[(fq * 4 + r) * SSTR + wn + in * 16 + fr] = f2bf(accw[in][r]);
  }
  __syncthreads();

  // ---- scan: 4 threads per column, 32 t-steps each, 16-step warmup ----
  const int col   = tid & 127;
  const int chunk = tid >> 7;           // 0..3
  const float av  = a[n0 + col];
  float h = 0.f;
  if (!(m0 == 0 && chunk == 0)) {
#pragma unroll
    for (int i = 0; i < 16; ++i)
      h = av * h + bf2f(Sl[(chunk * 32 + i) * SSTR + col]);
  }
  float* op = out + (size_t)(m0 + chunk * 32) * HDIM + n0 + col;
#pragma unroll
  for (int i = 0; i < 32; ++i) {
    h = av * h + bf2f(Sl[(chunk * 32 + 16 + i) * SSTR + col]);
    op[(size_t)i * HDIM] = h;
  }
}

extern "C" void kernel_launch(void* const* d_in, const int* in_sizes, int n_in,
                              void* d_out, int out_size, void* d_ws, size_t ws_size,
                              hipStream_t stream) {
  const float* x = (const float*)d_in[0];   // (T, H)
  const float* a = (const float*)d_in[1];   // (H,)
  const float* B = (const float*)d_in[2];   // (H, H)
  float* out = (float*)d_out;               // (1, T, H) fp32

  uint16_t* xb  = (uint16_t*)d_ws;                                        // 16 MB
  uint16_t* Btb = (uint16_t*)((char*)d_ws + (size_t)16 * 1024 * 1024);    //  8 MB

  // x -> bf16  and  B -> Bt bf16 (fused)
  prep<<<4096 + 1024, 256, 0, stream>>>(x, B, xb, Btb);
  // fused GEMM + recurrence: 512 blocks x 512 threads
  gemm_scan<<<dim3(HDIM / BN, TDIM / BM), 512, 0, stream>>>(xb, Btb, a, out);
}

// Round 7
// 138.725 us; speedup vs baseline: 1.0778x; 1.0059x over previous
//
#include <hip/hip_runtime.h>
#include <stdint.h>

// Problem dims
#define TDIM 4096
#define HDIM 2048   // N and K of the GEMM

// GEMM tile
#define BM 128
#define BN 128
#define BK 64
#define NKT (HDIM / BK)   // 32
// LDS: per buffer = A region (144 rows = 18 groups of 8 rows, 1KB/group)
//      + B region (128 rows = 16 groups), 128B per row (BK=64 bf16)
#define AREG  18432
#define PERBUF 34816
#define SSTR   132        // S-tile row stride in elements (breaks bank conflicts)

typedef short short8 __attribute__((ext_vector_type(8)));
typedef float f32x4 __attribute__((ext_vector_type(4)));

__device__ __forceinline__ uint16_t f2bf(float f) {
  uint32_t u = __builtin_bit_cast(uint32_t, f);
  u += 0x7fffu + ((u >> 16) & 1u);          // round-to-nearest-even
  return (uint16_t)(u >> 16);
}
__device__ __forceinline__ float bf2f(uint32_t h) {   // low 16 bits used
  uint32_t u = h << 16;
  return __builtin_bit_cast(float, u);
}

__device__ __forceinline__ void async_copy16(const void* gsrc, void* ldst) {
  __builtin_amdgcn_global_load_lds(
      (const __attribute__((address_space(1))) uint32_t*)gsrc,
      (__attribute__((address_space(3))) uint32_t*)ldst,
      16, 0, 0);
}

// ------------- prep: cvt x (fp32->bf16) + transpose/cvt B -> Bt -------------
__global__ void prep(const float* __restrict__ x, const float* __restrict__ B,
                     uint16_t* __restrict__ xb, uint16_t* __restrict__ Bt) {
  __shared__ uint16_t tile[64][68];
  const int t = threadIdx.x;
  if (blockIdx.x < 4096) {
    size_t i = ((size_t)blockIdx.x * 256 + t) * 8;
    float4 v0 = *(const float4*)(x + i);
    float4 v1 = *(const float4*)(x + i + 4);
    union { uint16_t h[8]; uint4 v; } o;
    o.h[0] = f2bf(v0.x); o.h[1] = f2bf(v0.y); o.h[2] = f2bf(v0.z); o.h[3] = f2bf(v0.w);
    o.h[4] = f2bf(v1.x); o.h[5] = f2bf(v1.y); o.h[6] = f2bf(v1.z); o.h[7] = f2bf(v1.w);
    *(uint4*)(xb + i) = o.v;
  } else {
    const int bid = blockIdx.x - 4096;
    const int n0 = (bid & 31) * 64;
    const int k0 = (bid >> 5) * 64;
    {
      const int r  = t >> 4;
      const int c4 = (t & 15) * 4;
#pragma unroll
      for (int i = 0; i < 4; ++i) {
        int rr = r + i * 16;
        float4 v = *(const float4*)&B[(size_t)(k0 + rr) * HDIM + n0 + c4];
        union { uint16_t h[4]; uint2 u; } o;
        o.h[0] = f2bf(v.x); o.h[1] = f2bf(v.y); o.h[2] = f2bf(v.z); o.h[3] = f2bf(v.w);
        *(uint2*)&tile[rr][c4] = o.u;
      }
    }
    __syncthreads();
    {
      const int nr = t >> 2;
      const int kc = (t & 3) * 4;
#pragma unroll
      for (int i = 0; i < 4; ++i) {
        int kk = kc + i * 16;
        union { uint16_t h[4]; uint2 u; } o;
        o.h[0] = tile[kk][nr];     o.h[1] = tile[kk + 1][nr];
        o.h[2] = tile[kk + 2][nr]; o.h[3] = tile[kk + 3][nr];
        *(uint2*)&Bt[(size_t)(n0 + nr) * HDIM + k0 + kk] = o.u;
      }
    }
  }
}

// --------- fused GEMM + causal exp-decay recurrence (scan) ---------
// S[t][n] = sum_k A[t][k]*Bt[n][k]; out[t][h] = S[t][h] + a[h]*out[t-1][h].
// 256 threads = 4 waves, each a 64x64 tile (4x4 acc): LDS reads/MFMA 1.5x
// lower than 64x32 tiles -> per-CU/iter traffic 204 KB (2 blocks/CU), the
// LDS-bw floor. BK=64: 128B rows + XOR-8 chunk swizzle = conflict-free.
// 16 warmup rows on waves 0,1; in-LDS S-tile scan epilogue (|a| <= 2^-5).
__global__ __launch_bounds__(256, 2) void gemm_scan(
    const uint16_t* __restrict__ A, const uint16_t* __restrict__ Bt,
    const float* __restrict__ a, float* __restrict__ out) {
  __shared__ __align__(16) char lds[2 * PERBUF];   // 69632 >= 144*132*2=38016

  const int tid  = threadIdx.x;
  const int lane = tid & 63;
  const int wave = tid >> 6;            // 0..3
  const int wm = (wave >> 1) * 64;      // wave row offset {0,64}
  const int wn = (wave & 1) * 64;       // wave col offset {0,64}
  const int m0 = blockIdx.y * BM;
  const int n0 = blockIdx.x * BN;

  f32x4 acc[4][4] = {};
  f32x4 accw[4] = {};                   // warmup rows (waves 0,1 only)

  // staging: one instr = 8 rows x 128B (1KB); lane l: row lr=l>>3, slot l&7,
  // fetches global chunk (l&7)^lr -> LDS slot c of row r holds chunk c^(r&7)
  const int lr = lane >> 3;             // 0..7
  const int gc = (lane & 7) ^ lr;       // swizzled 16B chunk to fetch

  const int fr = lane & 15;
  const int fq = lane >> 4;             // 0..3

  // A: 18 groups of 8 rows (t in [m0-16, m0+128)); wave w takes g=4w..4w+3,
  // waves 0,1 additionally take g=16,17.  B: 16 groups; wave w takes g=4w..4w+3.
  auto issue_tile = [&](int kt2) {
    size_t koff = (size_t)kt2 * (BK * 2);
    char* dst = lds + (kt2 & 1) * PERBUF;
#pragma unroll
    for (int i = 0; i < 4; ++i) {
      int g = wave * 4 + i;
      int row = m0 - 16 + g * 8 + lr;
      if (row < 0) row = 0;             // m0==0: garbage rows, never used
      async_copy16((const char*)A + ((size_t)row * HDIM + gc * 8) * 2 + koff,
                   dst + g * 1024);
    }
    if (wave < 2) {
      int g = 16 + wave;
      int row = m0 - 16 + g * 8 + lr;   // rows m0+112..m0+127: always valid
      async_copy16((const char*)A + ((size_t)row * HDIM + gc * 8) * 2 + koff,
                   dst + g * 1024);
    }
#pragma unroll
    for (int i = 0; i < 4; ++i) {
      int g = wave * 4 + i;
      int row = n0 + g * 8 + lr;
      async_copy16((const char*)Bt + ((size_t)row * HDIM + gc * 8) * 2 + koff,
                   dst + AREG + g * 1024);
    }
  };

  issue_tile(0);
  for (int kt = 0; kt < NKT; ++kt) {
    if (kt + 1 < NKT) {
      issue_tile(kt + 1);
      // wait only this tile's loads; next tile's (9 or 8) stay in flight
      if (wave < 2) asm volatile("s_waitcnt vmcnt(9)" ::: "memory");
      else          asm volatile("s_waitcnt vmcnt(8)" ::: "memory");
    } else {
      asm volatile("s_waitcnt vmcnt(0)" ::: "memory");
    }
    asm volatile("s_barrier" ::: "memory");

    const char* base = lds + (kt & 1) * PERBUF;
#pragma unroll
    for (int s = 0; s < 2; ++s) {       // two K=32 halves of the 128B row
      short8 af[4], bfr[4], aw;
#pragma unroll
      for (int im = 0; im < 4; ++im) {
        int row = 16 + wm + im * 16 + fr;               // row&7 == fr&7
        af[im] = *(const short8*)(base + row * 128 + (((s * 4 + fq) ^ (fr & 7)) * 16));
      }
#pragma unroll
      for (int in = 0; in < 4; ++in) {
        int row = wn + in * 16 + fr;
        bfr[in] = *(const short8*)(base + AREG + row * 128 + (((s * 4 + fq) ^ (fr & 7)) * 16));
      }
#pragma unroll
      for (int im = 0; im < 4; ++im)
#pragma unroll
        for (int in = 0; in < 4; ++in)
          acc[im][in] = __builtin_amdgcn_mfma_f32_16x16x32_bf16(
              af[im], bfr[in], acc[im][in], 0, 0, 0);
      if (wave < 2) {                   // warmup rows t in [m0-16, m0)
        aw = *(const short8*)(base + fr * 128 + (((s * 4 + fq) ^ (fr & 7)) * 16));
#pragma unroll
        for (int in = 0; in < 4; ++in)
          accw[in] = __builtin_amdgcn_mfma_f32_16x16x32_bf16(
              aw, bfr[in], accw[in], 0, 0, 0);
      }
    }

    asm volatile("s_barrier" ::: "memory");   // buf consumed; safe to refill
  }

  // ---- epilogue: S-tile (144 x 128, bf16, stride 132) into LDS ----
  uint16_t* Sl = (uint16_t*)lds;
#pragma unroll
  for (int im = 0; im < 4; ++im)
#pragma unroll
    for (int in = 0; in < 4; ++in)
#pragma unroll
      for (int r = 0; r < 4; ++r)
        Sl[(16 + wm + im * 16 + fq * 4 + r) * SSTR + wn + in * 16 + fr] =
            f2bf(acc[im][in][r]);
  if (wave < 2) {
#pragma unroll
    for (int in = 0; in < 4; ++in)
#pragma unroll
      for (int r = 0; r < 4; ++r)
        Sl[(fq * 4 + r) * SSTR + wn + in * 16 + fr] = f2bf(accw[in][r]);
  }
  __syncthreads();

  // ---- scan: 2 threads per column, 64 t-steps each, 16-step warmup ----
  const int col   = tid & 127;
  const int chunk = tid >> 7;           // 0 or 1
  const float av  = a[n0 + col];
  float h = 0.f;
  if (!(m0 == 0 && chunk == 0)) {
#pragma unroll
    for (int i = 0; i < 16; ++i)
      h = av * h + bf2f(Sl[(chunk * 64 + i) * SSTR + col]);
  }
  float* op = out + (size_t)(m0 + chunk * 64) * HDIM + n0 + col;
#pragma unroll
  for (int i = 0; i < 64; ++i) {
    h = av * h + bf2f(Sl[(chunk * 64 + 16 + i) * SSTR + col]);
    op[(size_t)i * HDIM] = h;
  }
}

extern "C" void kernel_launch(void* const* d_in, const int* in_sizes, int n_in,
                              void* d_out, int out_size, void* d_ws, size_t ws_size,
                              hipStream_t stream) {
  const float* x = (const float*)d_in[0];   // (T, H)
  const float* a = (const float*)d_in[1];   // (H,)
  const float* B = (const float*)d_in[2];   // (H, H)
  float* out = (float*)d_out;               // (1, T, H) fp32

  uint16_t* xb  = (uint16_t*)d_ws;                                        // 16 MB
  uint16_t* Btb = (uint16_t*)((char*)d_ws + (size_t)16 * 1024 * 1024);    //  8 MB

  // x -> bf16  and  B -> Bt bf16 (fused)
  prep<<<4096 + 1024, 256, 0, stream>>>(x, B, xb, Btb);
  // fused GEMM + recurrence: 512 blocks x 256 threads
  gemm_scan<<<dim3(HDIM / BN, TDIM / BM), 256, 0, stream>>>(xb, Btb, a, out);
}